// Round 4
// baseline (251.871 us; speedup 1.0000x reference)
//
#include <hip/hip_runtime.h>

typedef __attribute__((ext_vector_type(8))) short bf16x8;
typedef __attribute__((ext_vector_type(4))) float f32x4;
typedef __attribute__((ext_vector_type(8))) unsigned short ushort8;

#define N_BLADES 32
#define B_DIM 1024
#define IN_DIM 256
#define OUT_DIM 256
#define K_DIM (IN_DIM * N_BLADES)   // 8192
#define N_DIM (OUT_DIM * N_BLADES)  // 8192

// ---------- helpers ----------

__device__ __forceinline__ unsigned short f2bf(float f) {
    unsigned int u = __float_as_uint(f);
    u = (u + 0x7fff + ((u >> 16) & 1)) >> 16;   // RNE
    return (unsigned short)u;
}

__device__ __forceinline__ float gp_sign(int a, int b) {
    int swaps = 0;
#pragma unroll
    for (int i = 0; i < 5; ++i) {
        int mask = (~((1 << (i + 1)) - 1)) & 31;
        swaps += ((b >> i) & 1) * __popc(a & mask);
    }
    float s = (swaps & 1) ? -1.0f : 1.0f;
    if (a & b & 16) s = -s;
    return s;
}

__device__ __forceinline__ void gload_lds16(const void* g, void* l) {
    __builtin_amdgcn_global_load_lds(
        (const __attribute__((address_space(1))) unsigned int*)g,
        (__attribute__((address_space(3))) unsigned int*)l, 16, 0, 0);
}

#define FENCE() asm volatile("" ::: "memory")
#define BAR()   { FENCE(); __builtin_amdgcn_s_barrier(); FENCE(); }
#define LGKM0() asm volatile("s_waitcnt lgkmcnt(0)" ::: "memory")
#define VMC6()  asm volatile("s_waitcnt vmcnt(6)" ::: "memory")
#define VMC8()  asm volatile("s_waitcnt vmcnt(8)" ::: "memory")
#define PRIO1() __builtin_amdgcn_s_setprio(1)
#define PRIO0() __builtin_amdgcn_s_setprio(0)

// ---------- prep 1: cast x fp32 -> bf16 (unchanged, known-good) ----------
__global__ __launch_bounds__(256) void cast_x_kernel(const float4* __restrict__ x,
                                                     unsigned short* __restrict__ xb) {
    int t = blockIdx.x * 256 + threadIdx.x;
    float4 a = x[t * 2];
    float4 b = x[t * 2 + 1];
    ushort8 pk;
    pk[0] = f2bf(a.x); pk[1] = f2bf(a.y); pk[2] = f2bf(a.z); pk[3] = f2bf(a.w);
    pk[4] = f2bf(b.x); pk[5] = f2bf(b.y); pk[6] = f2bf(b.z); pk[7] = f2bf(b.w);
    *(ushort8*)(xb + (size_t)t * 8) = pk;
}

// ---------- prep 2: build w_g (unchanged, known-good) ----------
__global__ __launch_bounds__(256) void build_wg_kernel(const float* __restrict__ w,
                                                       unsigned short* __restrict__ wg) {
    __shared__ float sgn[1024];
    int tid = threadIdx.x;
    for (int idx = tid; idx < 1024; idx += 256) {
        sgn[idx] = gp_sign(idx >> 5, idx & 31);
    }
    __syncthreads();

    long t = (long)blockIdx.x * 256 + tid;
    int q   = (int)(t & 3);
    int i   = (int)((t >> 2) & 255);
    int row = (int)(t >> 10);
    int k = row & 31;
    int o = row >> 5;
    int j = k & 7;
    int g = (q * 8) ^ (k & 24);

    const float4* w4 = (const float4*)(w + ((long)(o * 256 + i) * 32 + g));
    float4 va = w4[0], vb = w4[1];
    float v0[8] = {va.x, va.y, va.z, va.w, vb.x, vb.y, vb.z, vb.w};
    float v1[8], v2[8], v3[8];
#pragma unroll
    for (int e = 0; e < 8; ++e) v1[e] = (j & 4) ? v0[e ^ 4] : v0[e];
#pragma unroll
    for (int e = 0; e < 8; ++e) v2[e] = (j & 2) ? v1[e ^ 2] : v1[e];
#pragma unroll
    for (int e = 0; e < 8; ++e) v3[e] = (j & 1) ? v2[e ^ 1] : v2[e];

    ushort8 pk;
#pragma unroll
    for (int e = 0; e < 8; ++e) {
        int mp = q * 8 + e;
        int a  = mp ^ k;
        pk[e] = f2bf(v3[e] * sgn[a * 32 + mp]);
    }
    *(ushort8*)(wg + (long)row * K_DIM + i * 32 + q * 8) = pk;
}

// ================= split-K GEMM: BM=256 BN=256 BK=64, wave tile 128x64 =================
// grid (32, 4, 2), 512 threads (8 waves 2Mx4N). Each block: K-half of 4096 (64 K-tiles).
// LDS: 2 buffers x (A 256x64 + B 256x64) bf16 = 2 x 64KB = 128KB.
// Per tile: 4 phases x {4-12 ds_read | bar | lgkm0 | 16 MFMA | bar}, then an 8-load
// stage burst for tile t+2 into the just-freed buffer + vmcnt(8) (counted, never 0).
// Swizzle byte ^= (row&7)<<4 both-sides (pre-swizzled global source, swizzled reads).

#define ROWB 16384                 // K_DIM*2 bytes per row
#define SKBUF 65536                // bytes per buffer (A 32KB + B 32KB)

__global__ __launch_bounds__(512, 2) void gemm_sk_kernel(const unsigned short* __restrict__ A,
                                                         const unsigned short* __restrict__ Bt,
                                                         float* __restrict__ C0,
                                                         float* __restrict__ C1) {
    __shared__ unsigned short lds[2 * SKBUF / 2];   // 128KB

    const int tid  = threadIdx.x;
    const int lane = tid & 63;
    const int wid  = tid >> 6;
    const int wr   = wid >> 2;          // 0..1 -> rows wr*128
    const int wc   = wid & 3;           // 0..3 -> cols wc*64
    const int l15  = lane & 15;
    const int l4   = lane >> 4;
    const int swzf = (l15 & 7) << 4;

    const int  z    = blockIdx.z;
    float* __restrict__ C = z ? C1 : C0;
    const long row0 = (long)blockIdx.y * 256;
    const long col0 = (long)blockIdx.x * 256;
    const long zoff = (long)z * 8192;   // byte offset of this K-half within a row

    const int  rr    = tid >> 3;        // 0..63: row within a 64-row issue-block
    const int  tid16 = tid * 16;
    const int  scb   = ((tid & 7) * 16) ^ ((rr & 7) << 4);
    const char* aSrc = (const char*)A  + (row0 + rr) * ROWB + scb;
    const char* bSrc = (const char*)Bt + (col0 + rr) * ROWB + scb;

#define SK_STAGE(bufbyte, gkb) { \
    _Pragma("unroll") for (int n = 0; n < 4; ++n) \
        gload_lds16(aSrc + (long)n * (64L * ROWB) + (gkb), (char*)lds + (bufbyte) + n * 8192 + tid16); \
    _Pragma("unroll") for (int n = 0; n < 4; ++n) \
        gload_lds16(bSrc + (long)n * (64L * ROWB) + (gkb), (char*)lds + (bufbyte) + 32768 + n * 8192 + tid16); }

    f32x4 acc[8][4];
#pragma unroll
    for (int mi = 0; mi < 8; ++mi)
#pragma unroll
        for (int ni = 0; ni < 4; ++ni) acc[mi][ni] = (f32x4)0.0f;

    bf16x8 aP[4];       // A frags for current phase (4 Mfrags, one kk)
    bf16x8 bF[4][2];    // all B frags for current tile

#define SK_READ_B(bufbyte) \
    _Pragma("unroll") for (int ni = 0; ni < 4; ++ni) \
    _Pragma("unroll") for (int kk = 0; kk < 2; ++kk) { \
        int r = wc * 64 + ni * 16 + l15; \
        bF[ni][kk] = *(const bf16x8*)((const char*)lds + (bufbyte) + 32768 + r * 128 + ((kk * 64 + l4 * 16) ^ swzf)); }
#define SK_READ_A4(bufbyte, mh, kk) \
    _Pragma("unroll") for (int u = 0; u < 4; ++u) { \
        int r = wr * 128 + ((mh) * 4 + u) * 16 + l15; \
        aP[u] = *(const bf16x8*)((const char*)lds + (bufbyte) + r * 128 + (((kk) * 64 + l4 * 16) ^ swzf)); }
#define SK_MFMA16(mh, kk) \
    _Pragma("unroll") for (int u = 0; u < 4; ++u) \
    _Pragma("unroll") for (int ni = 0; ni < 4; ++ni) \
        acc[(mh) * 4 + u][ni] = __builtin_amdgcn_mfma_f32_16x16x32_bf16( \
            aP[u], bF[ni][(kk)], acc[(mh) * 4 + u][ni], 0, 0, 0);

#define SK_TILE(bufbyte, kpb) { \
    SK_READ_B(bufbyte); SK_READ_A4(bufbyte, 0, 0); \
    BAR(); LGKM0(); PRIO1(); SK_MFMA16(0, 0); PRIO0(); BAR(); \
    SK_READ_A4(bufbyte, 1, 0); \
    BAR(); LGKM0(); PRIO1(); SK_MFMA16(1, 0); PRIO0(); BAR(); \
    SK_READ_A4(bufbyte, 0, 1); \
    BAR(); LGKM0(); PRIO1(); SK_MFMA16(0, 1); PRIO0(); BAR(); \
    SK_READ_A4(bufbyte, 1, 1); \
    BAR(); LGKM0(); PRIO1(); SK_MFMA16(1, 1); PRIO0(); BAR(); \
    SK_STAGE(bufbyte, kpb); VMC8(); BAR(); }

    // prologue: stage tiles 0 and 1
    SK_STAGE(0, zoff);
    SK_STAGE(SKBUF, zoff + 128);
    VMC8();
    BAR();

    long kp = zoff + 256;   // byte k-offset of tile t+2
    for (int t = 0; t < 64; t += 2) {
        SK_TILE(0, kp);
        kp += 128; if (kp == zoff + 8192) kp = zoff;
        SK_TILE(SKBUF, kp);
        kp += 128; if (kp == zoff + 8192) kp = zoff;
    }

    // epilogue: C/D layout col=lane&15, row=(lane>>4)*4+j
    const int cr = l4 * 4;
#pragma unroll
    for (int mi = 0; mi < 8; ++mi)
#pragma unroll
        for (int ni = 0; ni < 4; ++ni)
#pragma unroll
            for (int j = 0; j < 4; ++j) {
                long r = row0 + wr * 128 + mi * 16 + cr + j;
                long c = col0 + wc * 64 + ni * 16 + l15;
                C[r * N_DIM + c] = acc[mi][ni][j];
            }

#undef SK_STAGE
#undef SK_READ_B
#undef SK_READ_A4
#undef SK_MFMA16
#undef SK_TILE
}

// ---------- reduce: out += part ----------
__global__ __launch_bounds__(256) void reduce_kernel(float4* __restrict__ out,
                                                     const float4* __restrict__ part) {
    const int total = (B_DIM * N_DIM) / 4;   // 2097152
    for (int i = blockIdx.x * 256 + threadIdx.x; i < total; i += gridDim.x * 256) {
        float4 a = out[i], b = part[i];
        a.x += b.x; a.y += b.y; a.z += b.z; a.w += b.w;
        out[i] = a;
    }
}

// ================= R3 path (fallback if ws too small for split-K) =================
#define TILE_ELEMS 24576           // (128+256)*64
#define A64 ((long)64 * K_DIM * 2)
#define NT (K_DIM / 64)

__global__ __launch_bounds__(512, 2) void gemm8p_kernel(const unsigned short* __restrict__ A,
                                                        const unsigned short* __restrict__ Bt,
                                                        float* __restrict__ C) {
    __shared__ unsigned short lds[3 * TILE_ELEMS];

    const int tid  = threadIdx.x;
    const int lane = tid & 63;
    const int wid  = tid >> 6;
    const int wr   = wid >> 2;
    const int wc   = wid & 3;
    const int l15  = lane & 15;
    const int l4   = lane >> 4;
    const int swzf = (l15 & 7) << 4;

    const long row0 = (long)blockIdx.y * 128;
    const long col0 = (long)blockIdx.x * 256;

    const int  rr    = tid >> 3;
    const int  tid16 = tid * 16;
    const int  scb   = ((tid & 7) * 16) ^ ((rr & 7) << 4);
    const char* aSrc = (const char*)A  + (row0 + rr) * K_DIM * 2 + scb;
    const char* bSrc = (const char*)Bt + (col0 + rr) * K_DIM * 2 + scb;

    unsigned short* p0 = lds;
    unsigned short* p1 = lds + TILE_ELEMS;
    unsigned short* p2 = lds + 2 * TILE_ELEMS;

#define STAGE_A(pbuf, gk) { \
    gload_lds16(aSrc + (gk),       (char*)(pbuf) + tid16); \
    gload_lds16(aSrc + A64 + (gk), (char*)(pbuf) + 8192 + tid16); }
#define STAGE_B2(pbuf, gk, j0) { \
    gload_lds16(bSrc + (j0)*A64 + (gk),     (char*)(pbuf) + 16384 + (j0)*8192 + tid16); \
    gload_lds16(bSrc + ((j0)+1)*A64 + (gk), (char*)(pbuf) + 16384 + ((j0)+1)*8192 + tid16); }

    f32x4 acc[4][4];
#pragma unroll
    for (int mi = 0; mi < 4; ++mi)
#pragma unroll
        for (int ni = 0; ni < 4; ++ni) acc[mi][ni] = (f32x4)0.0f;

    bf16x8 aF[4][2];
    bf16x8 bF0[2][2];
    bf16x8 bF1[2][2];

#define READ_A_ALL() \
    _Pragma("unroll") for (int mi = 0; mi < 4; ++mi) \
    _Pragma("unroll") for (int kk = 0; kk < 2; ++kk) { \
        int r = wr * 64 + mi * 16 + l15; \
        aF[mi][kk] = *(const bf16x8*)((const char*)p0 + r * 128 + ((kk * 64 + l4 * 16) ^ swzf)); }
#define READ_B0() \
    _Pragma("unroll") for (int v = 0; v < 2; ++v) \
    _Pragma("unroll") for (int kk = 0; kk < 2; ++kk) { \
        int r = wc * 64 + v * 16 + l15; \
        bF0[v][kk] = *(const bf16x8*)((const char*)p0 + 16384 + r * 128 + ((kk * 64 + l4 * 16) ^ swzf)); }
#define READ_B1() \
    _Pragma("unroll") for (int v = 0; v < 2; ++v) \
    _Pragma("unroll") for (int kk = 0; kk < 2; ++kk) { \
        int r = wc * 64 + 32 + v * 16 + l15; \
        bF1[v][kk] = *(const bf16x8*)((const char*)p0 + 16384 + r * 128 + ((kk * 64 + l4 * 16) ^ swzf)); }
#define MFMA16_H0() \
    _Pragma("unroll") for (int mi = 0; mi < 4; ++mi) \
    _Pragma("unroll") for (int v = 0; v < 2; ++v) \
    _Pragma("unroll") for (int kk = 0; kk < 2; ++kk) \
        acc[mi][v] = __builtin_amdgcn_mfma_f32_16x16x32_bf16( \
            aF[mi][kk], bF0[v][kk], acc[mi][v], 0, 0, 0);
#define MFMA16_H1() \
    _Pragma("unroll") for (int mi = 0; mi < 4; ++mi) \
    _Pragma("unroll") for (int v = 0; v < 2; ++v) \
    _Pragma("unroll") for (int kk = 0; kk < 2; ++kk) \
        acc[mi][2 + v] = __builtin_amdgcn_mfma_f32_16x16x32_bf16( \
            aF[mi][kk], bF1[v][kk], acc[mi][2 + v], 0, 0, 0);

    STAGE_A(p0, 0); STAGE_B2(p0, 0, 0); STAGE_B2(p0, 0, 2);
    STAGE_A(p1, 128); STAGE_B2(p1, 128, 0); STAGE_B2(p1, 128, 2);
    VMC6();
    BAR();

    long kpre = 256;
    for (int t = 0; t < NT; ++t) {
        READ_A_ALL();
        READ_B0();
        STAGE_A(p2, kpre);
        STAGE_B2(p2, kpre, 0);
        BAR(); LGKM0(); PRIO1(); MFMA16_H0(); PRIO0(); BAR();
        READ_B1();
        STAGE_B2(p2, kpre, 2);
        BAR(); LGKM0(); PRIO1(); MFMA16_H1(); PRIO0();
        VMC6();
        BAR();

        unsigned short* tmp = p0; p0 = p1; p1 = p2; p2 = tmp;
        kpre += 128;
        if (kpre == (long)NT * 128) kpre = 0;
    }

    const int cr = l4 * 4;
#pragma unroll
    for (int mi = 0; mi < 4; ++mi)
#pragma unroll
        for (int ni = 0; ni < 4; ++ni)
#pragma unroll
            for (int j = 0; j < 4; ++j) {
                long r = row0 + wr * 64 + mi * 16 + cr + j;
                long c = col0 + wc * 64 + ni * 16 + l15;
                C[r * N_DIM + c] = acc[mi][ni][j];
            }

#undef STAGE_A
#undef STAGE_B2
#undef READ_A_ALL
#undef READ_B0
#undef READ_B1
#undef MFMA16_H0
#undef MFMA16_H1
}

// ---------- fallback (ws tiny): direct fp32, correct but slow ----------
__global__ __launch_bounds__(256) void fallback_gp_kernel(const float* __restrict__ x,
                                                          const float* __restrict__ w,
                                                          float* __restrict__ out) {
    __shared__ float xs[IN_DIM * 32];
    __shared__ float tab[1024];
    int tid = threadIdx.x;
    for (int idx = tid; idx < 1024; idx += 256) {
        int m = idx >> 5, k = idx & 31;
        tab[idx] = gp_sign(m, m ^ k);
    }
    int b = blockIdx.x;
    const float4* xrow = (const float4*)(x + (long)b * K_DIM);
    float4* xs4 = (float4*)xs;
    for (int idx = tid; idx < 2048; idx += 256) xs4[idx] = xrow[idx];
    __syncthreads();

    int wid = tid >> 6, lane = tid & 63;
    int o = blockIdx.y * 8 + wid;
    int k = lane & 31, half = lane >> 5;
    float acc = 0.f;
    const float* wrow = w + (long)o * K_DIM + half * 4096;
    for (int i = 0; i < 128; ++i) {
        int ib = (half * 128 + i) * 32;
#pragma unroll
        for (int m = 0; m < 32; ++m) {
            acc += xs[ib + (m ^ k)] * tab[m * 32 + k] * wrow[i * 32 + m];
        }
    }
    acc += __shfl_down(acc, 32);
    if (half == 0) out[((long)b * OUT_DIM + o) * 32 + k] = acc;
}

// ---------- launch ----------
extern "C" void kernel_launch(void* const* d_in, const int* in_sizes, int n_in,
                              void* d_out, int out_size, void* d_ws, size_t ws_size,
                              hipStream_t stream) {
    const float* x = (const float*)d_in[0];
    const float* w = (const float*)d_in[1];
    float* out = (float*)d_out;

    const size_t xb_bytes   = (size_t)B_DIM * K_DIM * 2;        // 16 MiB
    const size_t wg_bytes   = (size_t)N_DIM * K_DIM * 2;        // 128 MiB
    const size_t part_bytes = (size_t)B_DIM * N_DIM * 4;        // 32 MiB
    const size_t need_r3    = xb_bytes + wg_bytes;              // 144 MiB
    const size_t need_sk    = need_r3 + part_bytes;             // 176 MiB

    if (ws_size >= need_r3) {
        unsigned short* xb = (unsigned short*)d_ws;
        unsigned short* wg = (unsigned short*)((char*)d_ws + xb_bytes);

        cast_x_kernel<<<dim3(4096), dim3(256), 0, stream>>>((const float4*)x, xb);
        build_wg_kernel<<<dim3(32768), dim3(256), 0, stream>>>(w, wg);

        if (ws_size >= need_sk) {
            float* part = (float*)((char*)d_ws + need_r3);
            gemm_sk_kernel<<<dim3(32, 4, 2), dim3(512), 0, stream>>>(xb, wg, out, part);
            reduce_kernel<<<dim3(2048), dim3(256), 0, stream>>>((float4*)out, (const float4*)part);
        } else {
            gemm8p_kernel<<<dim3(N_DIM / 256, B_DIM / 128), dim3(512), 0, stream>>>(xb, wg, out);
        }
    } else {
        fallback_gp_kernel<<<dim3(B_DIM, OUT_DIM / 8), dim3(256), 0, stream>>>(x, w, out);
    }
}

// Round 5
// 248.046 us; speedup vs baseline: 1.0154x; 1.0154x over previous
//
#include <hip/hip_runtime.h>

typedef __attribute__((ext_vector_type(8))) short bf16x8;
typedef __attribute__((ext_vector_type(4))) float f32x4;
typedef __attribute__((ext_vector_type(8))) unsigned short ushort8;

#define N_BLADES 32
#define B_DIM 1024
#define IN_DIM 256
#define OUT_DIM 256
#define K_DIM (IN_DIM * N_BLADES)   // 8192
#define N_DIM (OUT_DIM * N_BLADES)  // 8192

// ---------- helpers ----------

__device__ __forceinline__ unsigned short f2bf(float f) {
    unsigned int u = __float_as_uint(f);
    u = (u + 0x7fff + ((u >> 16) & 1)) >> 16;   // RNE
    return (unsigned short)u;
}

__device__ __forceinline__ float gp_sign(int a, int b) {
    int swaps = 0;
#pragma unroll
    for (int i = 0; i < 5; ++i) {
        int mask = (~((1 << (i + 1)) - 1)) & 31;
        swaps += ((b >> i) & 1) * __popc(a & mask);
    }
    float s = (swaps & 1) ? -1.0f : 1.0f;
    if (a & b & 16) s = -s;
    return s;
}

__device__ __forceinline__ void gload_lds16(const void* g, void* l) {
    __builtin_amdgcn_global_load_lds(
        (const __attribute__((address_space(1))) unsigned int*)g,
        (__attribute__((address_space(3))) unsigned int*)l, 16, 0, 0);
}

#define FENCE() asm volatile("" ::: "memory")
#define BAR()   { FENCE(); __builtin_amdgcn_s_barrier(); FENCE(); }
#define LGKM0() { asm volatile("s_waitcnt lgkmcnt(0)" ::: "memory"); __builtin_amdgcn_sched_barrier(0); }
#define LGKM4() { asm volatile("s_waitcnt lgkmcnt(4)" ::: "memory"); __builtin_amdgcn_sched_barrier(0); }
#define LGKM8() { asm volatile("s_waitcnt lgkmcnt(8)" ::: "memory"); __builtin_amdgcn_sched_barrier(0); }
#define VMC6()  asm volatile("s_waitcnt vmcnt(6)" ::: "memory")
#define VMC8()  asm volatile("s_waitcnt vmcnt(8)" ::: "memory")
#define PRIO1() __builtin_amdgcn_s_setprio(1)
#define PRIO0() __builtin_amdgcn_s_setprio(0)

// ---------- prep 1: cast x fp32 -> bf16 (unchanged, known-good) ----------
__global__ __launch_bounds__(256) void cast_x_kernel(const float4* __restrict__ x,
                                                     unsigned short* __restrict__ xb) {
    int t = blockIdx.x * 256 + threadIdx.x;
    float4 a = x[t * 2];
    float4 b = x[t * 2 + 1];
    ushort8 pk;
    pk[0] = f2bf(a.x); pk[1] = f2bf(a.y); pk[2] = f2bf(a.z); pk[3] = f2bf(a.w);
    pk[4] = f2bf(b.x); pk[5] = f2bf(b.y); pk[6] = f2bf(b.z); pk[7] = f2bf(b.w);
    *(ushort8*)(xb + (size_t)t * 8) = pk;
}

// ---------- prep 2: build w_g (unchanged, known-good) ----------
__global__ __launch_bounds__(256) void build_wg_kernel(const float* __restrict__ w,
                                                       unsigned short* __restrict__ wg) {
    __shared__ float sgn[1024];
    int tid = threadIdx.x;
    for (int idx = tid; idx < 1024; idx += 256) {
        sgn[idx] = gp_sign(idx >> 5, idx & 31);
    }
    __syncthreads();

    long t = (long)blockIdx.x * 256 + tid;
    int q   = (int)(t & 3);
    int i   = (int)((t >> 2) & 255);
    int row = (int)(t >> 10);
    int k = row & 31;
    int o = row >> 5;
    int j = k & 7;
    int g = (q * 8) ^ (k & 24);

    const float4* w4 = (const float4*)(w + ((long)(o * 256 + i) * 32 + g));
    float4 va = w4[0], vb = w4[1];
    float v0[8] = {va.x, va.y, va.z, va.w, vb.x, vb.y, vb.z, vb.w};
    float v1[8], v2[8], v3[8];
#pragma unroll
    for (int e = 0; e < 8; ++e) v1[e] = (j & 4) ? v0[e ^ 4] : v0[e];
#pragma unroll
    for (int e = 0; e < 8; ++e) v2[e] = (j & 2) ? v1[e ^ 2] : v1[e];
#pragma unroll
    for (int e = 0; e < 8; ++e) v3[e] = (j & 1) ? v2[e ^ 1] : v2[e];

    ushort8 pk;
#pragma unroll
    for (int e = 0; e < 8; ++e) {
        int mp = q * 8 + e;
        int a  = mp ^ k;
        pk[e] = f2bf(v3[e] * sgn[a * 32 + mp]);
    }
    *(ushort8*)(wg + (long)row * K_DIM + i * 32 + q * 8) = pk;
}

// ================= split-K GEMM: BM=256 BN=256 BK=64, wave tile 128x64 =================
// grid (32, 4, 2), 512 threads (8 waves 2Mx4N). Each block: K-half of 4096 (64 K-tiles).
// LDS: 2 buffers x (A 256x64 + B 256x64) bf16 = 2 x 64KB = 128KB.
// Schedule per tile (NO intra-tile barriers): issue 16 ds_reads (B kk0+kk1, A ph0+ph1),
// counted lgkmcnt(8)/(4)/(4)/(0) between 16-MFMA clusters so reads overlap MFMA
// (DS ops complete in order per wave -> counted waits are exact). Ping-pong A-frag regs.
// Buffer hand-off: BAR ; stage t+2 into freed buf ; vmcnt(8) ; BAR  (counted, never 0).
// Swizzle byte ^= (row&7)<<4 both-sides (pre-swizzled global source, swizzled reads).

#define ROWB 16384                 // K_DIM*2 bytes per row
#define SKBUF 65536                // bytes per buffer (A 32KB + B 32KB)

__global__ __launch_bounds__(512, 2) void gemm_sk_kernel(const unsigned short* __restrict__ A,
                                                         const unsigned short* __restrict__ Bt,
                                                         float* __restrict__ C0,
                                                         float* __restrict__ C1) {
    __shared__ unsigned short lds[2 * SKBUF / 2];   // 128KB

    const int tid  = threadIdx.x;
    const int lane = tid & 63;
    const int wid  = tid >> 6;
    const int wr   = wid >> 2;          // 0..1 -> rows wr*128
    const int wc   = wid & 3;           // 0..3 -> cols wc*64
    const int l15  = lane & 15;
    const int l4   = lane >> 4;
    const int swzf = (l15 & 7) << 4;

    const int  z    = blockIdx.z;
    float* __restrict__ C = z ? C1 : C0;
    const long row0 = (long)blockIdx.y * 256;
    const long col0 = (long)blockIdx.x * 256;
    const long zoff = (long)z * 8192;   // byte offset of this K-half within a row

    const int  rr    = tid >> 3;        // 0..63: row within a 64-row issue-block
    const int  tid16 = tid * 16;
    const int  scb   = ((tid & 7) * 16) ^ ((rr & 7) << 4);
    const char* aSrc = (const char*)A  + (row0 + rr) * ROWB + scb;
    const char* bSrc = (const char*)Bt + (col0 + rr) * ROWB + scb;

#define SK_STAGE(bufbyte, gkb) { \
    _Pragma("unroll") for (int n = 0; n < 4; ++n) \
        gload_lds16(aSrc + (long)n * (64L * ROWB) + (gkb), (char*)lds + (bufbyte) + n * 8192 + tid16); \
    _Pragma("unroll") for (int n = 0; n < 4; ++n) \
        gload_lds16(bSrc + (long)n * (64L * ROWB) + (gkb), (char*)lds + (bufbyte) + 32768 + n * 8192 + tid16); }

    f32x4 acc[8][4];
#pragma unroll
    for (int mi = 0; mi < 8; ++mi)
#pragma unroll
        for (int ni = 0; ni < 4; ++ni) acc[mi][ni] = (f32x4)0.0f;

    bf16x8 aPing[4], aPong[4];  // ping-pong A-frag sets (static indexing only)
    bf16x8 bF[4][2];            // all B frags for current tile

#define SK_RB(bufbyte, kk) \
    _Pragma("unroll") for (int ni = 0; ni < 4; ++ni) { \
        int r = wc * 64 + ni * 16 + l15; \
        bF[ni][kk] = *(const bf16x8*)((const char*)lds + (bufbyte) + 32768 + r * 128 + (((kk) * 64 + l4 * 16) ^ swzf)); }
#define SK_RA(bufbyte, mh, kk, dst) \
    _Pragma("unroll") for (int u = 0; u < 4; ++u) { \
        int r = wr * 128 + (mh) * 64 + u * 16 + l15; \
        dst[u] = *(const bf16x8*)((const char*)lds + (bufbyte) + r * 128 + (((kk) * 64 + l4 * 16) ^ swzf)); }
#define SK_MF(APREG, mh, kk) \
    _Pragma("unroll") for (int u = 0; u < 4; ++u) \
    _Pragma("unroll") for (int ni = 0; ni < 4; ++ni) \
        acc[(mh) * 4 + u][ni] = __builtin_amdgcn_mfma_f32_16x16x32_bf16( \
            APREG[u], bF[ni][(kk)], acc[(mh) * 4 + u][ni], 0, 0, 0);

// One K-tile: 16 reads up front w/ counted waits; 4x16 MFMA; 2 barriers at hand-off.
#define SK_TILE2(bufbyte, kpb) { \
    SK_RB(bufbyte, 0); SK_RA(bufbyte, 0, 0, aPing); \
    SK_RB(bufbyte, 1); SK_RA(bufbyte, 1, 0, aPong); \
    LGKM8(); PRIO1(); SK_MF(aPing, 0, 0); PRIO0(); \
    SK_RA(bufbyte, 0, 1, aPing); \
    LGKM4(); PRIO1(); SK_MF(aPong, 1, 0); PRIO0(); \
    SK_RA(bufbyte, 1, 1, aPong); \
    LGKM4(); PRIO1(); SK_MF(aPing, 0, 1); PRIO0(); \
    LGKM0(); PRIO1(); SK_MF(aPong, 1, 1); PRIO0(); \
    BAR(); \
    SK_STAGE(bufbyte, kpb); \
    VMC8(); \
    BAR(); }

    // prologue: stage tiles 0 and 1; wait tile 0 (tile 1's 8 loads stay in flight)
    SK_STAGE(0, zoff);
    SK_STAGE(SKBUF, zoff + 128);
    VMC8();
    BAR();

    long kp = zoff + 256;   // byte k-offset of tile t+2
    for (int t = 0; t < 64; t += 2) {
        SK_TILE2(0, kp);
        kp += 128; if (kp == zoff + 8192) kp = zoff;
        SK_TILE2(SKBUF, kp);
        kp += 128; if (kp == zoff + 8192) kp = zoff;
    }

    // epilogue: C/D layout col=lane&15, row=(lane>>4)*4+j
    const int cr = l4 * 4;
#pragma unroll
    for (int mi = 0; mi < 8; ++mi)
#pragma unroll
        for (int ni = 0; ni < 4; ++ni)
#pragma unroll
            for (int j = 0; j < 4; ++j) {
                long r = row0 + wr * 128 + mi * 16 + cr + j;
                long c = col0 + wc * 64 + ni * 16 + l15;
                C[r * N_DIM + c] = acc[mi][ni][j];
            }

#undef SK_STAGE
#undef SK_RB
#undef SK_RA
#undef SK_MF
#undef SK_TILE2
}

// ---------- reduce: out += part ----------
__global__ __launch_bounds__(256) void reduce_kernel(float4* __restrict__ out,
                                                     const float4* __restrict__ part) {
    const int total = (B_DIM * N_DIM) / 4;   // 2097152
    for (int i = blockIdx.x * 256 + threadIdx.x; i < total; i += gridDim.x * 256) {
        float4 a = out[i], b = part[i];
        a.x += b.x; a.y += b.y; a.z += b.z; a.w += b.w;
        out[i] = a;
    }
}

// ================= R3 path (fallback if ws too small for split-K) =================
#define TILE_ELEMS 24576           // (128+256)*64
#define A64 ((long)64 * K_DIM * 2)
#define NT (K_DIM / 64)

__global__ __launch_bounds__(512, 2) void gemm8p_kernel(const unsigned short* __restrict__ A,
                                                        const unsigned short* __restrict__ Bt,
                                                        float* __restrict__ C) {
    __shared__ unsigned short lds[3 * TILE_ELEMS];

    const int tid  = threadIdx.x;
    const int lane = tid & 63;
    const int wid  = tid >> 6;
    const int wr   = wid >> 2;
    const int wc   = wid & 3;
    const int l15  = lane & 15;
    const int l4   = lane >> 4;
    const int swzf = (l15 & 7) << 4;

    const long row0 = (long)blockIdx.y * 128;
    const long col0 = (long)blockIdx.x * 256;

    const int  rr    = tid >> 3;
    const int  tid16 = tid * 16;
    const int  scb   = ((tid & 7) * 16) ^ ((rr & 7) << 4);
    const char* aSrc = (const char*)A  + (row0 + rr) * K_DIM * 2 + scb;
    const char* bSrc = (const char*)Bt + (col0 + rr) * K_DIM * 2 + scb;

    unsigned short* p0 = lds;
    unsigned short* p1 = lds + TILE_ELEMS;
    unsigned short* p2 = lds + 2 * TILE_ELEMS;

#define STAGE_A(pbuf, gk) { \
    gload_lds16(aSrc + (gk),       (char*)(pbuf) + tid16); \
    gload_lds16(aSrc + A64 + (gk), (char*)(pbuf) + 8192 + tid16); }
#define STAGE_B2(pbuf, gk, j0) { \
    gload_lds16(bSrc + (j0)*A64 + (gk),     (char*)(pbuf) + 16384 + (j0)*8192 + tid16); \
    gload_lds16(bSrc + ((j0)+1)*A64 + (gk), (char*)(pbuf) + 16384 + ((j0)+1)*8192 + tid16); }

    f32x4 acc[4][4];
#pragma unroll
    for (int mi = 0; mi < 4; ++mi)
#pragma unroll
        for (int ni = 0; ni < 4; ++ni) acc[mi][ni] = (f32x4)0.0f;

    bf16x8 aF[4][2];
    bf16x8 bF0[2][2];
    bf16x8 bF1[2][2];

#define READ_A_ALL() \
    _Pragma("unroll") for (int mi = 0; mi < 4; ++mi) \
    _Pragma("unroll") for (int kk = 0; kk < 2; ++kk) { \
        int r = wr * 64 + mi * 16 + l15; \
        aF[mi][kk] = *(const bf16x8*)((const char*)p0 + r * 128 + ((kk * 64 + l4 * 16) ^ swzf)); }
#define READ_B0() \
    _Pragma("unroll") for (int v = 0; v < 2; ++v) \
    _Pragma("unroll") for (int kk = 0; kk < 2; ++kk) { \
        int r = wc * 64 + v * 16 + l15; \
        bF0[v][kk] = *(const bf16x8*)((const char*)p0 + 16384 + r * 128 + ((kk * 64 + l4 * 16) ^ swzf)); }
#define READ_B1() \
    _Pragma("unroll") for (int v = 0; v < 2; ++v) \
    _Pragma("unroll") for (int kk = 0; kk < 2; ++kk) { \
        int r = wc * 64 + 32 + v * 16 + l15; \
        bF1[v][kk] = *(const bf16x8*)((const char*)p0 + 16384 + r * 128 + ((kk * 64 + l4 * 16) ^ swzf)); }
#define MFMA16_H0() \
    _Pragma("unroll") for (int mi = 0; mi < 4; ++mi) \
    _Pragma("unroll") for (int v = 0; v < 2; ++v) \
    _Pragma("unroll") for (int kk = 0; kk < 2; ++kk) \
        acc[mi][v] = __builtin_amdgcn_mfma_f32_16x16x32_bf16( \
            aF[mi][kk], bF0[v][kk], acc[mi][v], 0, 0, 0);
#define MFMA16_H1() \
    _Pragma("unroll") for (int mi = 0; mi < 4; ++mi) \
    _Pragma("unroll") for (int v = 0; v < 2; ++v) \
    _Pragma("unroll") for (int kk = 0; kk < 2; ++kk) \
        acc[mi][2 + v] = __builtin_amdgcn_mfma_f32_16x16x32_bf16( \
            aF[mi][kk], bF1[v][kk], acc[mi][2 + v], 0, 0, 0);

    STAGE_A(p0, 0); STAGE_B2(p0, 0, 0); STAGE_B2(p0, 0, 2);
    STAGE_A(p1, 128); STAGE_B2(p1, 128, 0); STAGE_B2(p1, 128, 2);
    VMC6();
    BAR();

    long kpre = 256;
    for (int t = 0; t < NT; ++t) {
        READ_A_ALL();
        READ_B0();
        STAGE_A(p2, kpre);
        STAGE_B2(p2, kpre, 0);
        BAR(); LGKM0(); PRIO1(); MFMA16_H0(); PRIO0(); BAR();
        READ_B1();
        STAGE_B2(p2, kpre, 2);
        BAR(); LGKM0(); PRIO1(); MFMA16_H1(); PRIO0();
        VMC6();
        BAR();

        unsigned short* tmp = p0; p0 = p1; p1 = p2; p2 = tmp;
        kpre += 128;
        if (kpre == (long)NT * 128) kpre = 0;
    }

    const int cr = l4 * 4;
#pragma unroll
    for (int mi = 0; mi < 4; ++mi)
#pragma unroll
        for (int ni = 0; ni < 4; ++ni)
#pragma unroll
            for (int j = 0; j < 4; ++j) {
                long r = row0 + wr * 64 + mi * 16 + cr + j;
                long c = col0 + wc * 64 + ni * 16 + l15;
                C[r * N_DIM + c] = acc[mi][ni][j];
            }

#undef STAGE_A
#undef STAGE_B2
#undef READ_A_ALL
#undef READ_B0
#undef READ_B1
#undef MFMA16_H0
#undef MFMA16_H1
}

// ---------- fallback (ws tiny): direct fp32, correct but slow ----------
__global__ __launch_bounds__(256) void fallback_gp_kernel(const float* __restrict__ x,
                                                          const float* __restrict__ w,
                                                          float* __restrict__ out) {
    __shared__ float xs[IN_DIM * 32];
    __shared__ float tab[1024];
    int tid = threadIdx.x;
    for (int idx = tid; idx < 1024; idx += 256) {
        int m = idx >> 5, k = idx & 31;
        tab[idx] = gp_sign(m, m ^ k);
    }
    int b = blockIdx.x;
    const float4* xrow = (const float4*)(x + (long)b * K_DIM);
    float4* xs4 = (float4*)xs;
    for (int idx = tid; idx < 2048; idx += 256) xs4[idx] = xrow[idx];
    __syncthreads();

    int wid = tid >> 6, lane = tid & 63;
    int o = blockIdx.y * 8 + wid;
    int k = lane & 31, half = lane >> 5;
    float acc = 0.f;
    const float* wrow = w + (long)o * K_DIM + half * 4096;
    for (int i = 0; i < 128; ++i) {
        int ib = (half * 128 + i) * 32;
#pragma unroll
        for (int m = 0; m < 32; ++m) {
            acc += xs[ib + (m ^ k)] * tab[m * 32 + k] * wrow[i * 32 + m];
        }
    }
    acc += __shfl_down(acc, 32);
    if (half == 0) out[((long)b * OUT_DIM + o) * 32 + k] = acc;
}

// ---------- launch ----------
extern "C" void kernel_launch(void* const* d_in, const int* in_sizes, int n_in,
                              void* d_out, int out_size, void* d_ws, size_t ws_size,
                              hipStream_t stream) {
    const float* x = (const float*)d_in[0];
    const float* w = (const float*)d_in[1];
    float* out = (float*)d_out;

    const size_t xb_bytes   = (size_t)B_DIM * K_DIM * 2;        // 16 MiB
    const size_t wg_bytes   = (size_t)N_DIM * K_DIM * 2;        // 128 MiB
    const size_t part_bytes = (size_t)B_DIM * N_DIM * 4;        // 32 MiB
    const size_t need_r3    = xb_bytes + wg_bytes;              // 144 MiB
    const size_t need_sk    = need_r3 + part_bytes;             // 176 MiB

    if (ws_size >= need_r3) {
        unsigned short* xb = (unsigned short*)d_ws;
        unsigned short* wg = (unsigned short*)((char*)d_ws + xb_bytes);

        cast_x_kernel<<<dim3(4096), dim3(256), 0, stream>>>((const float4*)x, xb);
        build_wg_kernel<<<dim3(32768), dim3(256), 0, stream>>>(w, wg);

        if (ws_size >= need_sk) {
            float* part = (float*)((char*)d_ws + need_r3);
            gemm_sk_kernel<<<dim3(32, 4, 2), dim3(512), 0, stream>>>(xb, wg, out, part);
            reduce_kernel<<<dim3(2048), dim3(256), 0, stream>>>((float4*)out, (const float4*)part);
        } else {
            gemm8p_kernel<<<dim3(N_DIM / 256, B_DIM / 128), dim3(512), 0, stream>>>(xb, wg, out);
        }
    } else {
        fallback_gp_kernel<<<dim3(B_DIM, OUT_DIM / 8), dim3(256), 0, stream>>>(x, w, out);
    }
}

// Round 6
// 155.148 us; speedup vs baseline: 1.6234x; 1.5988x over previous
//
#include <hip/hip_runtime.h>

typedef __attribute__((ext_vector_type(8))) short bf16x8;
typedef __attribute__((ext_vector_type(4))) float f32x4;
typedef __attribute__((ext_vector_type(8))) unsigned short ushort8;

#define N_BLADES 32
#define B_DIM 1024
#define IN_DIM 256
#define OUT_DIM 256
#define K_DIM (IN_DIM * N_BLADES)   // 8192
#define N_DIM (OUT_DIM * N_BLADES)  // 8192

// ---------- helpers ----------

__device__ __forceinline__ unsigned short f2bf(float f) {
    unsigned int u = __float_as_uint(f);
    u = (u + 0x7fff + ((u >> 16) & 1)) >> 16;   // RNE
    return (unsigned short)u;
}

__device__ __forceinline__ float gp_sign(int a, int b) {
    int swaps = 0;
#pragma unroll
    for (int i = 0; i < 5; ++i) {
        int mask = (~((1 << (i + 1)) - 1)) & 31;
        swaps += ((b >> i) & 1) * __popc(a & mask);
    }
    float s = (swaps & 1) ? -1.0f : 1.0f;
    if (a & b & 16) s = -s;
    return s;
}

__device__ __forceinline__ void gload_lds16(const void* g, void* l) {
    __builtin_amdgcn_global_load_lds(
        (const __attribute__((address_space(1))) unsigned int*)g,
        (__attribute__((address_space(3))) unsigned int*)l, 16, 0, 0);
}

#define FENCE() asm volatile("" ::: "memory")
#define BAR()    { FENCE(); __builtin_amdgcn_s_barrier(); FENCE(); }
#define SCHED0() __builtin_amdgcn_sched_barrier(0)
#define LGKM(n)  { asm volatile("s_waitcnt lgkmcnt(" #n ")" ::: "memory"); SCHED0(); }
#define VMC(n)   { asm volatile("s_waitcnt vmcnt(" #n ")" ::: "memory"); SCHED0(); }
#define PRIO1()  __builtin_amdgcn_s_setprio(1)
#define PRIO0()  __builtin_amdgcn_s_setprio(0)

// ---------- prep: cast fp32 -> bf16 (8 elems/thread) ----------
__global__ __launch_bounds__(256) void cast_kernel(const float4* __restrict__ x,
                                                   unsigned short* __restrict__ xb) {
    int t = blockIdx.x * 256 + threadIdx.x;
    float4 a = x[t * 2];
    float4 b = x[t * 2 + 1];
    ushort8 pk;
    pk[0] = f2bf(a.x); pk[1] = f2bf(a.y); pk[2] = f2bf(a.z); pk[3] = f2bf(a.w);
    pk[4] = f2bf(b.x); pk[5] = f2bf(b.y); pk[6] = f2bf(b.z); pk[7] = f2bf(b.w);
    *(ushort8*)(xb + (size_t)t * 8) = pk;
}

// ---------- uniform-j XOR shuffle + sign mask on a bf16 octet ----------
// dest[e] = src[e^j] ^ signbit(msk, e)
__device__ __forceinline__ bf16x8 shuffle_sign(bf16x8 v, int jx,
                                               unsigned int m0, unsigned int m1,
                                               unsigned int m2, unsigned int m3) {
    union { bf16x8 v8; unsigned int w[4]; } a, b;
    a.v8 = v;
    int s = jx >> 1;
    unsigned int t0 = (s & 1) ? a.w[1] : a.w[0];
    unsigned int t1 = (s & 1) ? a.w[0] : a.w[1];
    unsigned int t2 = (s & 1) ? a.w[3] : a.w[2];
    unsigned int t3 = (s & 1) ? a.w[2] : a.w[3];
    unsigned int u0 = (s & 2) ? t2 : t0;
    unsigned int u1 = (s & 2) ? t3 : t1;
    unsigned int u2 = (s & 2) ? t0 : t2;
    unsigned int u3 = (s & 2) ? t1 : t3;
    if (jx & 1) {
        u0 = (u0 >> 16) | (u0 << 16);
        u1 = (u1 >> 16) | (u1 << 16);
        u2 = (u2 >> 16) | (u2 << 16);
        u3 = (u3 >> 16) | (u3 << 16);
    }
    b.w[0] = u0 ^ m0; b.w[1] = u1 ^ m1; b.w[2] = u2 ^ m2; b.w[3] = u3 ^ m3;
    return b.v8;
}

// ================= GEMM, N ordered (k,o): Cws[b][k*256+o] =================
// Block = one k (blockIdx.x) x 128 b-rows (blockIdx.y). BM=128 BN=256 BK=64.
// B-operand = w_bf[o][K] direct (no permute), staged via global_load_lds,
//   pre-swizzled source + swizzled ds_read (involution).
// A-operand = x[b][m^k]*sign(m,m^k): reg-staged from xb with octet-XOR source
//   address, uniform-j register shuffle, sign-bit XOR mask; ds_write swizzled.
// 3 LDS buffers x (A 16KB + B 32KB) = 144KB. 1 barrier/tile; counted waits.

#define ABUF 16384
#define TBUF 49152
#define ROWB 16384    // bytes per K-row (8192 bf16)

__global__ __launch_bounds__(512, 1) void gemm_ko_kernel(const unsigned short* __restrict__ xb,
                                                         const unsigned short* __restrict__ wb,
                                                         float* __restrict__ Cws) {
    __shared__ char lds[3 * TBUF];

    const int tid  = threadIdx.x;
    const int lane = tid & 63;
    const int wid  = tid >> 6;
    const int wr   = wid >> 2;          // 0..1
    const int wc   = wid & 3;           // 0..3
    const int l15  = lane & 15;
    const int l4   = lane >> 4;
    const int swzf = (l15 & 7) << 4;

    const int  kblk = blockIdx.x;       // the k of this block
    const long row0 = (long)blockIdx.y * 128;
    const int  jx   = kblk & 7;
    const int  khi  = kblk & 24;

    // ---- A reg-staging constants: thread owns octets (2*tid, 2*tid+1), same row
    const int rowA = tid >> 2;                       // (2*tid)>>3
    const int h0   = (2 * tid) & 7;                  // even
    const int q0   = h0 & 3, q1 = (h0 + 1) & 3;
    const int aoff0 = ((h0 >> 2) * 64) + (((q0 * 8) ^ khi) * 2);
    const int aoff1 = (((h0 + 1) >> 2) * 64) + (((q1 * 8) ^ khi) * 2);
    const int adst0 = rowA * 128 + ((h0 * 16) ^ ((rowA & 7) << 4));
    const int adst1 = rowA * 128 + (((h0 + 1) * 16) ^ ((rowA & 7) << 4));
    const char* aSrcK = (const char*)xb + (row0 + rowA) * ROWB;

    unsigned int mA00, mA01, mA02, mA03, mA10, mA11, mA12, mA13;
    {
        unsigned int mk[2][4];
#pragma unroll
        for (int u = 0; u < 2; ++u) {
            int q = u ? q1 : q0;
#pragma unroll
            for (int w = 0; w < 4; ++w) {
                unsigned int mword = 0;
#pragma unroll
                for (int e2 = 0; e2 < 2; ++e2) {
                    int m = 8 * q + 2 * w + e2;
                    if (gp_sign(m, m ^ kblk) < 0.0f) mword |= 0x8000u << (16 * e2);
                }
                mk[u][w] = mword;
            }
        }
        mA00 = mk[0][0]; mA01 = mk[0][1]; mA02 = mk[0][2]; mA03 = mk[0][3];
        mA10 = mk[1][0]; mA11 = mk[1][1]; mA12 = mk[1][2]; mA13 = mk[1][3];
    }

    // ---- B staging constants (gload_lds, pre-swizzled source)
    const int  rrB   = tid >> 3;
    const int  tid16 = tid * 16;
    const int  scbB  = ((tid & 7) * 16) ^ ((rrB & 7) << 4);
    const char* bSrc = (const char*)wb + (long)rrB * ROWB + scbB;

    char* buf0 = lds;
    char* buf1 = lds + TBUF;
    char* buf2 = lds + 2 * TBUF;

#define B_STAGE(nbuf, kpb) { \
    _Pragma("unroll") for (int n = 0; n < 4; ++n) \
        gload_lds16(bSrc + (long)n * (64L * ROWB) + (kpb), (char*)(nbuf) + ABUF + n * 8192 + tid16); }
#define A_LOAD(kpb) { \
    rA0 = *(const bf16x8*)(aSrcK + (kpb) + aoff0); \
    rA1 = *(const bf16x8*)(aSrcK + (kpb) + aoff1); }
#define A_SHUF_WRITE(nbuf) { \
    bf16x8 s0 = shuffle_sign(rA0, jx, mA00, mA01, mA02, mA03); \
    bf16x8 s1 = shuffle_sign(rA1, jx, mA10, mA11, mA12, mA13); \
    *(bf16x8*)((char*)(nbuf) + adst0) = s0; \
    *(bf16x8*)((char*)(nbuf) + adst1) = s1; }
#define READ_AB(pbuf, kk, AS, BS) { \
    _Pragma("unroll") for (int mi = 0; mi < 4; ++mi) { \
        int r = wr * 64 + mi * 16 + l15; \
        AS[mi] = *(const bf16x8*)((const char*)(pbuf) + r * 128 + (((kk) * 64 + l4 * 16) ^ swzf)); } \
    _Pragma("unroll") for (int ni = 0; ni < 4; ++ni) { \
        int r = wc * 64 + ni * 16 + l15; \
        BS[ni] = *(const bf16x8*)((const char*)(pbuf) + ABUF + r * 128 + (((kk) * 64 + l4 * 16) ^ swzf)); } }
#define MFMA16(AS, BS) \
    _Pragma("unroll") for (int mi = 0; mi < 4; ++mi) \
    _Pragma("unroll") for (int ni = 0; ni < 4; ++ni) \
        acc[mi][ni] = __builtin_amdgcn_mfma_f32_16x16x32_bf16(AS[mi], BS[ni], acc[mi][ni], 0, 0, 0);

    f32x4 acc[4][4];
#pragma unroll
    for (int mi = 0; mi < 4; ++mi)
#pragma unroll
        for (int ni = 0; ni < 4; ++ni) acc[mi][ni] = (f32x4)0.0f;

    bf16x8 rA0, rA1;
    bf16x8 aF0[4], bF0[4], aF1[4], bF1[4];

    // ---- prologue: tile0 fully staged; tile1 staged (B in flight); rA(1) loaded
    A_LOAD(0);
    VMC(0);
    A_SHUF_WRITE(buf0);
    SCHED0();
    B_STAGE(buf0, 0);
    SCHED0();
    A_LOAD(128);
    SCHED0();
    B_STAGE(buf1, 128);
    SCHED0();
    VMC(6);            // B(0) done; pending: rA(1) 2 + B(1) 4
    LGKM(0);           // A(0) writes done
    BAR();

    char* pc = buf0; char* pn = buf1; char* ps = buf2;
    int kp = 256;      // byte K-offset of tile t+2
    for (int t = 0; t < 128; ++t) {
        READ_AB(pc, 0, aF0, bF0);
        SCHED0();
        READ_AB(pc, 1, aF1, bF1);
        VMC(4);                 // rA(t+1) ready (B(t+1)'s 4 may pend)
        A_SHUF_WRITE(pn);       // 2 ds_write: A for tile t+1
        SCHED0();
        A_LOAD(kp);             // 2 global: rA(t+2)
        SCHED0();
        B_STAGE(ps, kp);        // 4 gload_lds: B(t+2)
        SCHED0();
        LGKM(10); PRIO1(); MFMA16(aF0, bF0); PRIO0();
        LGKM(2);  PRIO1(); MFMA16(aF1, bF1); PRIO0();
        VMC(6);                 // B(t+1) complete; rA(t+2)+B(t+2) in flight
        LGKM(0);                // A(t+1) writes visible
        BAR();

        char* tmp = pc; pc = pn; pn = ps; ps = tmp;
        kp += 128;
        if (kp == 16384) kp = 0;
    }

    // epilogue: C/D layout col=lane&15, row=(lane>>4)*4+j
    const int cr = l4 * 4;
#pragma unroll
    for (int mi = 0; mi < 4; ++mi)
#pragma unroll
        for (int ni = 0; ni < 4; ++ni)
#pragma unroll
            for (int jj = 0; jj < 4; ++jj) {
                long r = row0 + wr * 64 + mi * 16 + cr + jj;
                int  c = kblk * 256 + wc * 64 + ni * 16 + l15;
                Cws[r * N_DIM + c] = acc[mi][ni][jj];
            }

#undef B_STAGE
#undef A_LOAD
#undef A_SHUF_WRITE
#undef READ_AB
#undef MFMA16
}

// ---------- transpose: out[b][o*32+k] = Cws[b][k*256+o] ----------
__global__ __launch_bounds__(256) void transpose_kernel(const float* __restrict__ Cws,
                                                        float* __restrict__ out) {
    __shared__ float t[32 * 260];
    const int tid = threadIdx.x;
    const long b  = blockIdx.x;
    const float4* src = (const float4*)(Cws + b * N_DIM);
    float4*       dst = (float4*)(out + b * N_DIM);
#pragma unroll
    for (int r = 0; r < 8; ++r) {
        int f = tid + r * 256;          // float4 index in row
        float4 v = src[f];
        int k  = f >> 6;
        int c4 = (f & 63) * 4;
        *(float4*)&t[k * 260 + c4] = v;
    }
    __syncthreads();
#pragma unroll
    for (int r = 0; r < 8; ++r) {
        int g  = tid + r * 256;         // out float4 index
        int o  = g >> 3;
        int k0 = (g & 7) * 4;
        float4 v;
        v.x = t[(k0 + 0) * 260 + o];
        v.y = t[(k0 + 1) * 260 + o];
        v.z = t[(k0 + 2) * 260 + o];
        v.w = t[(k0 + 3) * 260 + o];
        dst[g] = v;
    }
}

// ---------- fallback (ws tiny): direct fp32, correct but slow ----------
__global__ __launch_bounds__(256) void fallback_gp_kernel(const float* __restrict__ x,
                                                          const float* __restrict__ w,
                                                          float* __restrict__ out) {
    __shared__ float xs[IN_DIM * 32];
    __shared__ float tab[1024];
    int tid = threadIdx.x;
    for (int idx = tid; idx < 1024; idx += 256) {
        int m = idx >> 5, k = idx & 31;
        tab[idx] = gp_sign(m, m ^ k);
    }
    int b = blockIdx.x;
    const float4* xrow = (const float4*)(x + (long)b * K_DIM);
    float4* xs4 = (float4*)xs;
    for (int idx = tid; idx < 2048; idx += 256) xs4[idx] = xrow[idx];
    __syncthreads();

    int wid = tid >> 6, lane = tid & 63;
    int o = blockIdx.y * 8 + wid;
    int k = lane & 31, half = lane >> 5;
    float acc = 0.f;
    const float* wrow = w + (long)o * K_DIM + half * 4096;
    for (int i = 0; i < 128; ++i) {
        int ib = (half * 128 + i) * 32;
#pragma unroll
        for (int m = 0; m < 32; ++m) {
            acc += xs[ib + (m ^ k)] * tab[m * 32 + k] * wrow[i * 32 + m];
        }
    }
    acc += __shfl_down(acc, 32);
    if (half == 0) out[((long)b * OUT_DIM + o) * 32 + k] = acc;
}

// ---------- launch ----------
extern "C" void kernel_launch(void* const* d_in, const int* in_sizes, int n_in,
                              void* d_out, int out_size, void* d_ws, size_t ws_size,
                              hipStream_t stream) {
    const float* x = (const float*)d_in[0];
    const float* w = (const float*)d_in[1];
    float* out = (float*)d_out;

    const size_t xb_bytes  = (size_t)B_DIM * K_DIM * 2;        // 16 MiB
    const size_t wb_bytes  = (size_t)OUT_DIM * IN_DIM * 32 * 2; // 4.2 MB
    const size_t cw_bytes  = (size_t)B_DIM * N_DIM * 4;        // 32 MiB
    const size_t need = xb_bytes + wb_bytes + cw_bytes;        // ~54 MB

    if (ws_size >= need) {
        unsigned short* xbp = (unsigned short*)d_ws;
        unsigned short* wbp = (unsigned short*)((char*)d_ws + xb_bytes);
        float*          cws = (float*)((char*)d_ws + xb_bytes + wb_bytes);

        cast_kernel<<<dim3(4096), dim3(256), 0, stream>>>((const float4*)x, xbp);
        cast_kernel<<<dim3(1024), dim3(256), 0, stream>>>((const float4*)w, wbp);
        gemm_ko_kernel<<<dim3(32, 8), dim3(512), 0, stream>>>(xbp, wbp, cws);
        transpose_kernel<<<dim3(B_DIM), dim3(256), 0, stream>>>(cws, out);
    } else {
        fallback_gp_kernel<<<dim3(B_DIM, OUT_DIM / 8), dim3(256), 0, stream>>>(x, w, out);
    }
}